// Round 5
// baseline (426.945 us; speedup 1.0000x reference)
//
#include <hip/hip_runtime.h>
#include <math.h>

#define V 50257
#define E 1024
#define H 1024
#define L 512

// d_out offsets (floats): [log_probs V][h_new H][attn_weights L]
#define OUT_H  50257
#define OUT_AW 51281

// ws offsets (floats)
#define WS_S    0       // 512 exp(attn scores)
#define WS_SUM  512     // 1 float: sum of exp(scores)   (memset to 0 each launch)
#define WS_X    1024    // 2048 x = [embedded, attn_applied]
#define WS_GH   3072    // 3072 gh
#define WS_GI   6144    // 3072 gi
#define WS_BM   10240   // 1024 per-block maxes
#define WS_BS   12288   // 1024 per-block sumexps

__device__ __forceinline__ float dot4(const float4 a, const float4 b) {
    return a.x * b.x + a.y * b.y + a.z * b.z + a.w * b.w;
}

__device__ __forceinline__ float wave_sum(float v) {
    for (int off = 32; off > 0; off >>= 1) v += __shfl_down(v, off, 64);
    return v;
}

// K1: attn scores -> exp + global atomic sum (waves 0..511), gh (512..3583),
//     zero x[E:] (3584..3599), stage emb into x[0:E] (3600..3615). 904 blocks.
// exp without max-subtract is fp32-safe here: scores ~N(0,0.64), |s| < ~5.
__global__ void k1_scores_gh(const int* __restrict__ input,
                             const float* __restrict__ hidden,
                             const float* __restrict__ emb_table,
                             const float* __restrict__ attn_W,
                             const float* __restrict__ attn_b,
                             const float* __restrict__ W_hh,
                             const float* __restrict__ b_hh,
                             float* __restrict__ ws) {
    const int t = threadIdx.x;
    const int lane = t & 63;
    const int gwave = blockIdx.x * 4 + (t >> 6);
    const float4* h4 = (const float4*)hidden;
    const float* embrow = emb_table + (size_t)input[0] * E;

    if (gwave < L) {
        const float4* emb4 = (const float4*)embrow;
        const float4* w4 = (const float4*)(attn_W + (size_t)gwave * (E + H));
        float acc = 0.f;
#pragma unroll
        for (int k = 0; k < 8; ++k) {
            int i = lane + 64 * k;
            float4 a = (k < 4) ? emb4[i] : h4[i - E / 4];
            acc += dot4(a, w4[i]);
        }
        acc = wave_sum(acc);
        if (lane == 0) {
            float e = expf(acc + attn_b[gwave]);
            ws[WS_S + gwave] = e;
            atomicAdd(&ws[WS_SUM], e);
        }
    } else if (gwave < L + 3 * H) {
        int k = gwave - L;
        const float4* w4 = (const float4*)(W_hh + (size_t)k * H);
        float acc = 0.f;
#pragma unroll
        for (int ii = 0; ii < 4; ++ii) {
            int i = lane + 64 * ii;
            acc += dot4(h4[i], w4[i]);
        }
        acc = wave_sum(acc);
        if (lane == 0) ws[WS_GH + k] = acc + b_hh[k];
    } else if (gwave < 3600) {          // zero attn_applied accumulator
        ws[WS_X + E + (gwave - 3584) * 64 + lane] = 0.f;
    } else if (gwave < 3616) {          // stage embedded into x[0:E]
        int i = (gwave - 3600) * 64 + lane;
        ws[WS_X + i] = embrow[i];
    }
}

// K2: weights = e/sum (no reduce phases), then attn_applied slice.
//     128 blocks x 256: jc = blk&3 (j-chunk of 256), lc = blk>>2 (l-chunk of 16).
__global__ void k2_softmax_applied(const float* __restrict__ enc,
                                   float* __restrict__ ws,
                                   float* __restrict__ out) {
    __shared__ float w[512];
    const int t = threadIdx.x;

    float inv = 1.f / ws[WS_SUM];
    float w0 = ws[WS_S + t] * inv;
    float w1 = ws[WS_S + 256 + t] * inv;
    w[t] = w0;
    w[256 + t] = w1;
    if (blockIdx.x == 0) {
        out[OUT_AW + t] = w0;
        out[OUT_AW + 256 + t] = w1;
    }
    __syncthreads();

    const int j = (blockIdx.x & 3) * 256 + t;      // 4 j-chunks of 256
    const int l0 = (blockIdx.x >> 2) * 16;         // 32 l-chunks of 16
    float acc = 0.f;
#pragma unroll
    for (int l = l0; l < l0 + 16; ++l)
        acc += w[l] * enc[(size_t)l * H + j];
    atomicAdd(&ws[WS_X + E + j], acc);
}

// K3: gi = x @ W_ih^T + b_ih; one wave per row, 768 blocks x 256.
__global__ void k3_gi(const float* __restrict__ W_ih, const float* __restrict__ b_ih,
                      float* __restrict__ ws) {
    const int lane = threadIdx.x & 63;
    const int gwave = blockIdx.x * 4 + (threadIdx.x >> 6);
    const float4* x4 = (const float4*)(ws + WS_X);
    const float4* w4 = (const float4*)(W_ih + (size_t)gwave * (E + H));
    float acc = 0.f;
#pragma unroll
    for (int k = 0; k < 8; ++k) {
        int i = lane + 64 * k;
        acc += dot4(x4[i], w4[i]);
    }
    acc = wave_sum(acc);
    if (lane == 0) ws[WS_GI + gwave] = acc + b_ih[gwave];
}

// K4: 1024 blocks x 256 (4096 waves, 12-13 rows each; worst imbalance +8% vs +14%).
//     Explicit 1-deep row pipeline: row k+1 loads issue before row k's reduce.
//     out_b hoisted to one vector load per wave (off the (m,s) chain).
__global__ __launch_bounds__(256, 4)
void k4_logits(const float* __restrict__ hidden,
               const float* __restrict__ out_W,
               const float* __restrict__ out_b,
               float* __restrict__ ws,
               float* __restrict__ out) {
    __shared__ float hn[H];
    __shared__ float wm[4], wsum[4];
    const int t = threadIdx.x;
    const int lane = t & 63, wid = t >> 6;
    const int gwave = blockIdx.x * 4 + wid;            // 4096 waves
    const int nrows = 12 + (gwave < (V - 12 * 4096));  // V - 49152 = 1105

    // issue row-0 loads first: latency hides under the h_new preamble
    const float4* w4_0 = (const float4*)(out_W + (size_t)gwave * H);
    float4 c0 = w4_0[lane];
    float4 c1 = w4_0[lane + 64];
    float4 c2 = w4_0[lane + 128];
    float4 c3 = w4_0[lane + 192];

    // this wave's biases, one load: lane k holds out_b[gwave + k*4096]
    float ob = (lane < nrows) ? out_b[gwave + lane * 4096] : 0.f;

    // h_new computed redundantly (gi/gh/hidden are L2-hot, 28 KB)
#pragma unroll
    for (int c = 0; c < 4; ++c) {
        int k = t + 256 * c;
        float gir = ws[WS_GI + k],         ghr = ws[WS_GH + k];
        float giz = ws[WS_GI + H + k],     ghz = ws[WS_GH + H + k];
        float gin = ws[WS_GI + 2 * H + k], ghn = ws[WS_GH + 2 * H + k];
        float r = 1.f / (1.f + expf(-(gir + ghr)));
        float z = 1.f / (1.f + expf(-(giz + ghz)));
        float n = tanhf(gin + r * ghn);
        float v = (1.f - z) * n + z * hidden[k];
        hn[k] = v;
        if (blockIdx.x == 0) out[OUT_H + k] = v;
    }
    __syncthreads();

    // hoist this lane's hn fragment into registers (reused every row)
    const float4* hn4 = (const float4*)hn;
    float4 h0 = hn4[lane];
    float4 h1 = hn4[lane + 64];
    float4 h2 = hn4[lane + 128];
    float4 h3 = hn4[lane + 192];

    float m = -INFINITY, s = 0.f;
    for (int k = 0; k < nrows; ++k) {
        const int row = gwave + k * 4096;
        float4 n0, n1, n2, n3;
        const bool more = (k + 1 < nrows);
        if (more) {       // issue next-row loads before the reduce chain
            const float4* nx = (const float4*)(out_W + (size_t)(row + 4096) * H);
            n0 = nx[lane];
            n1 = nx[lane + 64];
            n2 = nx[lane + 128];
            n3 = nx[lane + 192];
        }
        float acc = dot4(h0, c0) + dot4(h1, c1) + dot4(h2, c2) + dot4(h3, c3);
        acc = wave_sum(acc);
        float obk = __shfl(ob, k, 64);
        if (lane == 0) {
            float lg = acc + obk;
            out[row] = lg;
            if (lg > m) { s = s * expf(m - lg) + 1.f; m = lg; }
            else        { s += expf(lg - m); }
        }
        if (more) { c0 = n0; c1 = n1; c2 = n2; c3 = n3; }
    }
    if (lane == 0) { wm[wid] = m; wsum[wid] = s; }
    __syncthreads();
    if (t == 0) {
        float M = fmaxf(fmaxf(wm[0], wm[1]), fmaxf(wm[2], wm[3]));
        float S = wsum[0] * expf(wm[0] - M) + wsum[1] * expf(wm[1] - M)
                + wsum[2] * expf(wm[2] - M) + wsum[3] * expf(wm[3] - M);
        ws[WS_BM + blockIdx.x] = M;
        ws[WS_BS + blockIdx.x] = S;
    }
}

// K5: each block redundantly combines the 1024 (m,s) pairs (8 KB, L2-hot),
//     then subtracts the logsumexp offset from its 256 logits. 197 blocks.
__global__ void k5_logprobs(const float* __restrict__ ws, float* __restrict__ out) {
    __shared__ float redm[4], reds[4];
    __shared__ float off_s;
    const int t = threadIdx.x;
    const int lane = t & 63, wid = t >> 6;
    float m = -INFINITY, s = 0.f;
#pragma unroll
    for (int c = 0; c < 4; ++c) {
        int b = t + 256 * c;                  // 1024 pairs
        float bm = ws[WS_BM + b], bs = ws[WS_BS + b];
        float M2 = fmaxf(m, bm);
        s = s * expf(m - M2) + bs * expf(bm - M2);
        m = M2;
    }
    for (int off = 32; off > 0; off >>= 1) {
        float mo = __shfl_down(m, off, 64);
        float so = __shfl_down(s, off, 64);
        float M2 = fmaxf(m, mo);
        s = s * expf(m - M2) + so * expf(mo - M2);
        m = M2;
    }
    if (lane == 0) { redm[wid] = m; reds[wid] = s; }
    __syncthreads();
    if (t == 0) {
        float M = redm[0], S = reds[0];
        for (int i = 1; i < 4; ++i) {
            float M2 = fmaxf(M, redm[i]);
            S = S * expf(M - M2) + reds[i] * expf(redm[i] - M2);
            M = M2;
        }
        off_s = M + logf(S);
    }
    __syncthreads();
    int i = blockIdx.x * 256 + t;
    if (i < V) out[i] -= off_s;
}

extern "C" void kernel_launch(void* const* d_in, const int* in_sizes, int n_in,
                              void* d_out, int out_size, void* d_ws, size_t ws_size,
                              hipStream_t stream) {
    const int*   input   = (const int*)d_in[0];
    const float* hidden  = (const float*)d_in[1];
    const float* enc     = (const float*)d_in[2];
    const float* emb     = (const float*)d_in[3];
    const float* attn_W  = (const float*)d_in[4];
    const float* attn_b  = (const float*)d_in[5];
    const float* W_ih    = (const float*)d_in[6];
    const float* W_hh    = (const float*)d_in[7];
    const float* b_ih    = (const float*)d_in[8];
    const float* b_hh    = (const float*)d_in[9];
    const float* out_W   = (const float*)d_in[10];
    const float* out_b   = (const float*)d_in[11];
    float* out = (float*)d_out;
    float* ws  = (float*)d_ws;

    // zero the exp-sum accumulator (4 B; capture-safe, proven in round 3)
    hipMemsetAsync((char*)d_ws + WS_SUM * sizeof(float), 0, sizeof(float), stream);

    k1_scores_gh<<<904, 256, 0, stream>>>(input, hidden, emb, attn_W, attn_b, W_hh, b_hh, ws);
    k2_softmax_applied<<<128, 256, 0, stream>>>(enc, ws, out);
    k3_gi<<<768, 256, 0, stream>>>(W_ih, b_ih, ws);
    k4_logits<<<1024, 256, 0, stream>>>(hidden, out_W, out_b, ws, out);
    k5_logprobs<<<197, 256, 0, stream>>>(ws, out);
}

// Round 6
// 419.285 us; speedup vs baseline: 1.0183x; 1.0183x over previous
//
#include <hip/hip_runtime.h>
#include <math.h>

#define V 50257
#define E 1024
#define H 1024
#define L 512

// d_out offsets (floats): [log_probs V][h_new H][attn_weights L]
#define OUT_H  50257
#define OUT_AW 51281

// ws offsets (floats)
#define WS_S    0       // 512 exp(attn scores)
#define WS_SUM  512     // 1 float: sum of exp(scores)   (memset to 0 each launch)
#define WS_X    1024    // 2048 x = [embedded, attn_applied]
#define WS_GH   3072    // 3072 gh
#define WS_GI   6144    // 3072 gi
#define WS_BM   10240   // 2048 per-block maxes
#define WS_BS   12288   // 2048 per-block sumexps

__device__ __forceinline__ float dot4(const float4 a, const float4 b) {
    return a.x * b.x + a.y * b.y + a.z * b.z + a.w * b.w;
}

__device__ __forceinline__ float wave_sum(float v) {
    for (int off = 32; off > 0; off >>= 1) v += __shfl_down(v, off, 64);
    return v;
}

// K1: attn scores -> exp, per-block reduce, 1 atomic/block (waves 0..511);
//     gh (512..3583); zero x[E:] (3584..3599); stage emb (3600..3615). 904 blocks.
// exp without max-subtract is fp32-safe: scores ~N(0,0.64), |s| < ~5.
__global__ void k1_scores_gh(const int* __restrict__ input,
                             const float* __restrict__ hidden,
                             const float* __restrict__ emb_table,
                             const float* __restrict__ attn_W,
                             const float* __restrict__ attn_b,
                             const float* __restrict__ W_hh,
                             const float* __restrict__ b_hh,
                             float* __restrict__ ws) {
    __shared__ float es[4];
    const int t = threadIdx.x;
    const int lane = t & 63;
    const int wid = t >> 6;
    const int gwave = blockIdx.x * 4 + wid;
    const float4* h4 = (const float4*)hidden;
    const float* embrow = emb_table + (size_t)input[0] * E;

    if (gwave < L) {                    // blocks 0..127: all 4 waves are score waves
        const float4* emb4 = (const float4*)embrow;
        const float4* w4 = (const float4*)(attn_W + (size_t)gwave * (E + H));
        float acc = 0.f;
#pragma unroll
        for (int k = 0; k < 8; ++k) {
            int i = lane + 64 * k;
            float4 a = (k < 4) ? emb4[i] : h4[i - E / 4];
            acc += dot4(a, w4[i]);
        }
        acc = wave_sum(acc);
        if (lane == 0) {
            float e = expf(acc + attn_b[gwave]);
            ws[WS_S + gwave] = e;
            es[wid] = e;
        }
        __syncthreads();                // uniform per block (all 4 waves in branch)
        if (t == 0) atomicAdd(&ws[WS_SUM], es[0] + es[1] + es[2] + es[3]);
    } else if (gwave < L + 3 * H) {
        int k = gwave - L;
        const float4* w4 = (const float4*)(W_hh + (size_t)k * H);
        float acc = 0.f;
#pragma unroll
        for (int ii = 0; ii < 4; ++ii) {
            int i = lane + 64 * ii;
            acc += dot4(h4[i], w4[i]);
        }
        acc = wave_sum(acc);
        if (lane == 0) ws[WS_GH + k] = acc + b_hh[k];
    } else if (gwave < 3600) {          // zero attn_applied accumulator
        ws[WS_X + E + (gwave - 3584) * 64 + lane] = 0.f;
    } else if (gwave < 3616) {          // stage embedded into x[0:E]
        int i = (gwave - 3600) * 64 + lane;
        ws[WS_X + i] = embrow[i];
    }
}

// K2: weights = e/sum (no reduce phases), then attn_applied slice.
//     128 blocks x 256: jc = blk&3 (j-chunk of 256), lc = blk>>2 (l-chunk of 16).
__global__ void k2_softmax_applied(const float* __restrict__ enc,
                                   float* __restrict__ ws,
                                   float* __restrict__ out) {
    __shared__ float w[512];
    const int t = threadIdx.x;

    float inv = 1.f / ws[WS_SUM];
    float w0 = ws[WS_S + t] * inv;
    float w1 = ws[WS_S + 256 + t] * inv;
    w[t] = w0;
    w[256 + t] = w1;
    if (blockIdx.x == 0) {
        out[OUT_AW + t] = w0;
        out[OUT_AW + 256 + t] = w1;
    }
    __syncthreads();

    const int j = (blockIdx.x & 3) * 256 + t;      // 4 j-chunks of 256
    const int l0 = (blockIdx.x >> 2) * 16;         // 32 l-chunks of 16
    float acc = 0.f;
#pragma unroll
    for (int l = l0; l < l0 + 16; ++l)
        acc += w[l] * enc[(size_t)l * H + j];
    atomicAdd(&ws[WS_X + E + j], acc);
}

// K3: gi = x @ W_ih^T + b_ih; one wave per row, 768 blocks x 256.
__global__ void k3_gi(const float* __restrict__ W_ih, const float* __restrict__ b_ih,
                      float* __restrict__ ws) {
    const int lane = threadIdx.x & 63;
    const int gwave = blockIdx.x * 4 + (threadIdx.x >> 6);
    const float4* x4 = (const float4*)(ws + WS_X);
    const float4* w4 = (const float4*)(W_ih + (size_t)gwave * (E + H));
    float acc = 0.f;
#pragma unroll
    for (int k = 0; k < 8; ++k) {
        int i = lane + 64 * k;
        acc += dot4(x4[i], w4[i]);
    }
    acc = wave_sum(acc);
    if (lane == 0) ws[WS_GI + gwave] = acc + b_ih[gwave];
}

// K4: round-4 structure (2048 blocks -> 8 blocks/CU co-resident, 32 waves/CU for
//     max outstanding loads on the out_W stream). Row-0 prefetch hides under the
//     h_new preamble; hn fragment in registers; out_b hoisted to one vector load
//     per wave and __shfl-broadcast (off the lane-0 (m,s) serial chain).
__global__ void k4_logits(const float* __restrict__ hidden,
                          const float* __restrict__ out_W,
                          const float* __restrict__ out_b,
                          float* __restrict__ ws,
                          float* __restrict__ out) {
    __shared__ float hn[H];
    __shared__ float wm[4], wsum[4];
    const int t = threadIdx.x;
    const int lane = t & 63, wid = t >> 6;
    const int gwave = blockIdx.x * 4 + wid;            // 8192 waves
    const int nrows = 6 + (gwave < (V - 6 * 8192));    // V - 49152 = 1105

    // issue row-0 loads first: independent, latency hides under the hn preamble
    const float4* w4_0 = (const float4*)(out_W + (size_t)gwave * H);
    float4 pre0 = w4_0[lane];
    float4 pre1 = w4_0[lane + 64];
    float4 pre2 = w4_0[lane + 128];
    float4 pre3 = w4_0[lane + 192];

    // this wave's biases, one load: lane k holds out_b[gwave + k*8192]
    float ob = (lane < nrows) ? out_b[gwave + (size_t)lane * 8192] : 0.f;

    // h_new computed redundantly (gi/gh/hidden are L2-hot, 28 KB)
#pragma unroll
    for (int c = 0; c < 4; ++c) {
        int k = t + 256 * c;
        float gir = ws[WS_GI + k],         ghr = ws[WS_GH + k];
        float giz = ws[WS_GI + H + k],     ghz = ws[WS_GH + H + k];
        float gin = ws[WS_GI + 2 * H + k], ghn = ws[WS_GH + 2 * H + k];
        float r = 1.f / (1.f + expf(-(gir + ghr)));
        float z = 1.f / (1.f + expf(-(giz + ghz)));
        float n = tanhf(gin + r * ghn);
        float v = (1.f - z) * n + z * hidden[k];
        hn[k] = v;
        if (blockIdx.x == 0) out[OUT_H + k] = v;
    }
    __syncthreads();

    // hoist this lane's hn fragment into registers (reused every row)
    const float4* hn4 = (const float4*)hn;
    float4 h0 = hn4[lane];
    float4 h1 = hn4[lane + 64];
    float4 h2 = hn4[lane + 128];
    float4 h3 = hn4[lane + 192];

    float m = -INFINITY, s = 0.f;

    // row 0 from prefetch registers
    {
        float acc = dot4(h0, pre0) + dot4(h1, pre1) + dot4(h2, pre2) + dot4(h3, pre3);
        acc = wave_sum(acc);
        float ob0 = __shfl(ob, 0, 64);
        if (lane == 0) {
            float lg = acc + ob0;
            out[gwave] = lg;
            m = lg; s = 1.f;
        }
    }
    // remaining rows
    for (int k = 1; k < nrows; ++k) {
        const int row = gwave + k * 8192;
        const float4* w4 = (const float4*)(out_W + (size_t)row * H);
        float acc = dot4(h0, w4[lane])
                  + dot4(h1, w4[lane + 64])
                  + dot4(h2, w4[lane + 128])
                  + dot4(h3, w4[lane + 192]);
        acc = wave_sum(acc);
        float obk = __shfl(ob, k, 64);
        if (lane == 0) {
            float lg = acc + obk;
            out[row] = lg;
            if (lg > m) { s = s * expf(m - lg) + 1.f; m = lg; }
            else        { s += expf(lg - m); }
        }
    }
    if (lane == 0) { wm[wid] = m; wsum[wid] = s; }
    __syncthreads();
    if (t == 0) {
        float M = fmaxf(fmaxf(wm[0], wm[1]), fmaxf(wm[2], wm[3]));
        float S = wsum[0] * expf(wm[0] - M) + wsum[1] * expf(wm[1] - M)
                + wsum[2] * expf(wm[2] - M) + wsum[3] * expf(wm[3] - M);
        ws[WS_BM + blockIdx.x] = M;
        ws[WS_BS + blockIdx.x] = S;
    }
}

// K5: each block redundantly combines the 2048 (m,s) pairs (16 KB, L2-hot),
//     then subtracts the logsumexp offset from its 256 logits. 197 blocks.
__global__ void k5_logprobs(const float* __restrict__ ws, float* __restrict__ out) {
    __shared__ float redm[4], reds[4];
    __shared__ float off_s;
    const int t = threadIdx.x;
    const int lane = t & 63, wid = t >> 6;
    float m = -INFINITY, s = 0.f;
#pragma unroll
    for (int c = 0; c < 8; ++c) {
        int b = t + 256 * c;                  // 2048 pairs
        float bm = ws[WS_BM + b], bs = ws[WS_BS + b];
        float M2 = fmaxf(m, bm);
        s = s * expf(m - M2) + bs * expf(bm - M2);
        m = M2;
    }
    for (int off = 32; off > 0; off >>= 1) {
        float mo = __shfl_down(m, off, 64);
        float so = __shfl_down(s, off, 64);
        float M2 = fmaxf(m, mo);
        s = s * expf(m - M2) + so * expf(mo - M2);
        m = M2;
    }
    if (lane == 0) { redm[wid] = m; reds[wid] = s; }
    __syncthreads();
    if (t == 0) {
        float M = redm[0], S = reds[0];
        for (int i = 1; i < 4; ++i) {
            float M2 = fmaxf(M, redm[i]);
            S = S * expf(M - M2) + reds[i] * expf(redm[i] - M2);
            M = M2;
        }
        off_s = M + logf(S);
    }
    __syncthreads();
    int i = blockIdx.x * 256 + t;
    if (i < V) out[i] -= off_s;
}

extern "C" void kernel_launch(void* const* d_in, const int* in_sizes, int n_in,
                              void* d_out, int out_size, void* d_ws, size_t ws_size,
                              hipStream_t stream) {
    const int*   input   = (const int*)d_in[0];
    const float* hidden  = (const float*)d_in[1];
    const float* enc     = (const float*)d_in[2];
    const float* emb     = (const float*)d_in[3];
    const float* attn_W  = (const float*)d_in[4];
    const float* attn_b  = (const float*)d_in[5];
    const float* W_ih    = (const float*)d_in[6];
    const float* W_hh    = (const float*)d_in[7];
    const float* b_ih    = (const float*)d_in[8];
    const float* b_hh    = (const float*)d_in[9];
    const float* out_W   = (const float*)d_in[10];
    const float* out_b   = (const float*)d_in[11];
    float* out = (float*)d_out;
    float* ws  = (float*)d_ws;

    // zero the exp-sum accumulator (4 B; capture-safe)
    hipMemsetAsync((char*)d_ws + WS_SUM * sizeof(float), 0, sizeof(float), stream);

    k1_scores_gh<<<904, 256, 0, stream>>>(input, hidden, emb, attn_W, attn_b, W_hh, b_hh, ws);
    k2_softmax_applied<<<128, 256, 0, stream>>>(enc, ws, out);
    k3_gi<<<768, 256, 0, stream>>>(W_ih, b_ih, ws);
    k4_logits<<<2048, 256, 0, stream>>>(hidden, out_W, out_b, ws, out);
    k5_logprobs<<<197, 256, 0, stream>>>(ws, out);
}